// Round 15
// baseline (66.458 us; speedup 1.0000x reference)
//
#include <hip/hip_runtime.h>
#include <math.h>

#define N_PTR 2048
#define M_NU  4096
#define DIM   512
#define KCLS  1000
#define KPAD  1024

static constexpr float LAMBDA_ = 0.1f;
static constexpr float EPS_ = 1e-8f;
static constexpr float INV_DENOM = 1.0f / (0.1f * 0.5f + 1e-8f);   // 1/(lambda*eps+EPS)

typedef short short8 __attribute__((ext_vector_type(8)));
typedef unsigned short u16x8 __attribute__((ext_vector_type(8)));
typedef float f32x4 __attribute__((ext_vector_type(4)));

__device__ __forceinline__ unsigned short f2bf(float x) {
  unsigned u = __float_as_uint(x);
  u += 0x7fff + ((u >> 16) & 1);     // round-to-nearest-even
  return (unsigned short)(u >> 16);
}
__device__ __forceinline__ float bf2f(unsigned short h) {
  return __uint_as_float(((unsigned)h) << 16);
}

__device__ __forceinline__ void gload16(const void* g, void* l) {
  __builtin_amdgcn_global_load_lds(
      (const __attribute__((address_space(1))) unsigned int*)g,
      (__attribute__((address_space(3))) unsigned int*)l, 16, 0, 0);
}

// ---------- block reduction helpers (blockDim.x == 256) ----------
__device__ __forceinline__ float blk_reduce_sum(float v, float* red) {
  #pragma unroll
  for (int off = 32; off > 0; off >>= 1) v += __shfl_down(v, off);
  __syncthreads();
  if ((threadIdx.x & 63) == 0) red[threadIdx.x >> 6] = v;
  __syncthreads();
  return red[0] + red[1] + red[2] + red[3];
}

__device__ __forceinline__ float blk_reduce_max(float v, float* red) {
  #pragma unroll
  for (int off = 32; off > 0; off >>= 1) v = fmaxf(v, __shfl_down(v, off));
  __syncthreads();
  if ((threadIdx.x & 63) == 0) red[threadIdx.x >> 6] = v;
  __syncthreads();
  return fmaxf(fmaxf(red[0], red[1]), fmaxf(red[2], red[3]));
}

// ---------- 1. fused prep: normalize+cast (blocks 0..1791) + CE loss (blocks 1792..5887) ----------
__global__ __launch_bounds__(256) void prep_kernel(
    const float* __restrict__ ptr_f, const float* __restrict__ nu_f,
    const float* __restrict__ cls_f, const float* __restrict__ logits,
    const int* __restrict__ labels, unsigned short* __restrict__ An,
    unsigned short* __restrict__ Bn, unsigned short* __restrict__ Cn,
    float* __restrict__ losses) {
  __shared__ float red[4];
  int b = blockIdx.x;
  if (b < 1792) {                       // ---- normalize + bf16 cast
    int gid = b * 256 + threadIdx.x;
    int row = gid >> 6, lane = gid & 63;
    const float* src; unsigned short* dst; int lrow; int in_rows;
    if (row < N_PTR)             { src = ptr_f; dst = An; lrow = row;                in_rows = N_PTR; }
    else if (row < N_PTR + M_NU) { src = nu_f;  dst = Bn; lrow = row - N_PTR;        in_rows = M_NU; }
    else                         { src = cls_f; dst = Cn; lrow = row - N_PTR - M_NU; in_rows = KCLS; }
    u16x8 ov;
    if (lrow < in_rows) {
      const float4* rp = (const float4*)(src + (size_t)lrow * DIM);
      float4 a = rp[lane * 2], bq = rp[lane * 2 + 1];
      float v[8] = {a.x, a.y, a.z, a.w, bq.x, bq.y, bq.z, bq.w};
      float s = 0.f;
      #pragma unroll
      for (int j = 0; j < 8; ++j) s = fmaf(v[j], v[j], s);
      #pragma unroll
      for (int off = 32; off > 0; off >>= 1) s += __shfl_xor(s, off);
      float inv = 1.0f / fmaxf(sqrtf(s), EPS_);
      #pragma unroll
      for (int j = 0; j < 8; ++j) ov[j] = f2bf(v[j] * inv);
    } else {
      #pragma unroll
      for (int j = 0; j < 8; ++j) ov[j] = 0;
    }
    *(u16x8*)(dst + (size_t)lrow * DIM + lane * 8) = ov;
  } else {                              // ---- CE loss (one block per nu row, float4 reads)
    int row = b - 1792;
    int tid = threadIdx.x;
    const float* x = logits + (size_t)row * KCLS;
    const float4* x4 = (const float4*)x;          // 4000B rows are 16B-aligned
    float4 v = make_float4(0.f, 0.f, 0.f, 0.f);
    float mx_loc = -INFINITY;
    if (tid < 250) {                              // 250*4 = 1000
      v = x4[tid];
      mx_loc = fmaxf(fmaxf(v.x, v.y), fmaxf(v.z, v.w));
    }
    float mx = blk_reduce_max(mx_loc, red);
    float se_loc = 0.f;
    if (tid < 250)
      se_loc = __expf(v.x - mx) + __expf(v.y - mx) + __expf(v.z - mx) + __expf(v.w - mx);
    float se = blk_reduce_sum(se_loc, red);
    if (tid == 0) losses[row] = mx + logf(se) - x[labels[row]];
  }
}

// ---------- 2. bf16 MFMA GEMM C = A @ B^T, tile BM x BN, BK=64, 4 waves 2x2 ----------
// MODE 0 (G-GEMM, 64x64): 2D grid; bf16 gram store; block(0,0) reduces gmax first.
// MODE 1 (S-GEMM, 128x64): 1D grid (1024 blocks = 4/CU, 16 waves/CU) with bijective
//   XCD-chunked swizzle; fused DRO epilogue identical to r10/r14.
template <int BM, int BN, int MODE>
__global__ __launch_bounds__(256) void mfma_gemm(
    const unsigned short* __restrict__ A, const unsigned short* __restrict__ B,
    unsigned short* __restrict__ Gfb, unsigned short* __restrict__ Tb,
    const int* __restrict__ pl, const int* __restrict__ nl,
    const float* __restrict__ nu_loss, unsigned* __restrict__ gbits,
    float* __restrict__ pr, float* __restrict__ pr2,
    float* __restrict__ s_part, float* __restrict__ gy_part, int ldc) {
  constexpr int FRM = BM / 32;         // A frags per wave (128->4, 64->2)
  constexpr int FRN = BN / 32;         // B frags per wave (64->2)
  __shared__ unsigned short Alds[BM * 64];
  __shared__ unsigned short Blds[BN * 64];
  __shared__ float red[4];
  const int tid = threadIdx.x;
  const int w = tid >> 6, lane = tid & 63;
  int bx, by;
  if (MODE == 1) {
    int swz = (blockIdx.x & 7) * 128 + (blockIdx.x >> 3);  // bijective, 1024 blocks
    bx = swz >> 4;                     // 0..63: XCD k owns bx in [8k, 8k+8)
    by = swz & 15;                     // 0..15
  } else {
    bx = blockIdx.x; by = blockIdx.y;
  }
  const int brow = by * BM, bcol = bx * BN;
  const int wr = w >> 1, wc = w & 1;

  if (MODE == 0 && blockIdx.x == 0 && blockIdx.y == 0) {
    float mloc = 0.f;
    for (int i = tid; i < M_NU; i += 256) mloc = fmaxf(mloc, nu_loss[i]);
    float mx = blk_reduce_max(mloc, red);
    if (tid == 0) *gbits = __float_as_uint(mx);
    __syncthreads();
  }

  const int sr = lane >> 3;            // row within 8-row staging group
  const int sc = lane & 7;             // 16B chunk within 128B row
  const int schunk = (sc ^ sr) * 8;    // pre-swizzled global element offset

  f32x4 acc[FRM][FRN] = {};

  for (int k0 = 0; k0 < DIM; k0 += 64) {
    #pragma unroll
    for (int i = 0; i < FRM; ++i) {
      int j = w * FRM + i;             // A staging slot, 8 rows each
      int r = j * 8 + sr;
      gload16(A + (size_t)(brow + r) * DIM + k0 + schunk, (char*)Alds + j * 1024);
    }
    #pragma unroll
    for (int i = 0; i < FRN; ++i) {
      int j = w * FRN + i;             // B staging slot, 8 rows each
      int r = j * 8 + sr;
      gload16(B + (size_t)(bcol + r) * DIM + k0 + schunk, (char*)Blds + j * 1024);
    }
    __syncthreads();
    #pragma unroll
    for (int kk = 0; kk < 2; ++kk) {
      const int koff = kk * 64 + (lane >> 4) * 16;
      short8 af[FRM], bfr[FRN];
      #pragma unroll
      for (int mi = 0; mi < FRM; ++mi) {
        int r = wr * (BM / 2) + mi * 16 + (lane & 15);
        af[mi] = *(const short8*)((const char*)Alds + r * 128 + (koff ^ ((r & 7) << 4)));
      }
      #pragma unroll
      for (int ni = 0; ni < FRN; ++ni) {
        int r = wc * (BN / 2) + ni * 16 + (lane & 15);
        bfr[ni] = *(const short8*)((const char*)Blds + r * 128 + (koff ^ ((r & 7) << 4)));
      }
      #pragma unroll
      for (int mi = 0; mi < FRM; ++mi)
        #pragma unroll
        for (int ni = 0; ni < FRN; ++ni)
          acc[mi][ni] = __builtin_amdgcn_mfma_f32_16x16x32_bf16(af[mi], bfr[ni], acc[mi][ni], 0, 0, 0);
    }
    __syncthreads();
  }

  // C/D layout: col = lane&15, row = (lane>>4)*4 + reg  [verified]
  if (MODE == 0) {
    #pragma unroll
    for (int mi = 0; mi < FRM; ++mi)
      #pragma unroll
      for (int ni = 0; ni < FRN; ++ni)
        #pragma unroll
        for (int j = 0; j < 4; ++j) {
          int row = brow + wr * (BM / 2) + mi * 16 + (lane >> 4) * 4 + j;
          int col = bcol + wc * (BN / 2) + ni * 16 + (lane & 15);
          Gfb[(size_t)row * ldc + col] = f2bf(acc[mi][ni][j]);
        }
  } else {
    const float gmax = __uint_as_float(*gbits);
    const float fac = LAMBDA_ * INV_DENOM;            // ~2
    int cols[FRN]; float a_r[FRN]; float loss_r[FRN]; int nl_r[FRN];
    #pragma unroll
    for (int ni = 0; ni < FRN; ++ni) {
      cols[ni]  = bcol + wc * (BN / 2) + ni * 16 + (lane & 15);
      loss_r[ni] = nu_loss[cols[ni]];
      a_r[ni]   = (loss_r[ni] - gmax - 2.f * LAMBDA_) * INV_DENOM;
      nl_r[ni]  = nl[cols[ni]];
    }
    float s_acc = 0.f, gy_acc = 0.f;
    #pragma unroll
    for (int mi = 0; mi < FRM; ++mi) {
      #pragma unroll
      for (int j = 0; j < 4; ++j) {
        int row = brow + wr * (BM / 2) + mi * 16 + (lane >> 4) * 4 + j;
        const unsigned short* Grow = Gfb + (size_t)pl[row] * KPAD;
        float rowacc = 0.f, rowacc2 = 0.f;
        #pragma unroll
        for (int ni = 0; ni < FRN; ++ni) {
          float s  = acc[mi][ni][j];
          float gy = bf2f(Grow[nl_r[ni]]);
          float e  = fmaf(fac, s + gy, a_r[ni]);
          float t  = __expf(e);
          unsigned short tb = f2bf(t);
          Tb[(size_t)row * ldc + cols[ni]] = tb;
          float tt = bf2f(tb);
          rowacc  += tt;
          rowacc2 += tt * loss_r[ni];
          s_acc += s; gy_acc += gy;
        }
        #pragma unroll
        for (int off = 1; off < 16; off <<= 1) {
          rowacc  += __shfl_xor(rowacc, off);
          rowacc2 += __shfl_xor(rowacc2, off);
        }
        if ((lane & 15) == 0) {
          pr [(size_t)(bx * 2 + wc) * N_PTR + row] = rowacc;
          pr2[(size_t)(bx * 2 + wc) * N_PTR + row] = rowacc2;
        }
      }
    }
    float stot = blk_reduce_sum(s_acc, red);
    float gtot = blk_reduce_sum(gy_acc, red);
    if (tid == 0) {
      int bid = by * 64 + bx;
      s_part[bid] = stot; gy_part[bid] = gtot;
    }
  }
}

// ---------- 3. colpass (blocks 0..255) + T/D row reduce (blocks 256..271) ----------
__global__ __launch_bounds__(256) void colpass_td_kernel(
    const unsigned short* __restrict__ Tb, const float* __restrict__ pr,
    const float* __restrict__ pr2, float* __restrict__ partial,
    float* __restrict__ T_part, float* __restrict__ D_part) {
  __shared__ float sh[64];
  int b = blockIdx.x, tid = threadIdx.x;
  if (b < 256) {                       // ---- column partial: 512 m-cols x 64 n-rows
    int bx = b & 7, by = b >> 3;
    int m0 = bx * 512 + tid * 2;
    int n0 = by * 64;
    if (tid < 64) {
      float rs = 0.f;
      #pragma unroll 4
      for (int cb = 0; cb < 128; ++cb) rs += pr[(size_t)cb * N_PTR + n0 + tid];
      sh[tid] = 1.0f / (rs + EPS_);
    }
    __syncthreads();
    float a0 = 0.f, a1 = 0.f;
    #pragma unroll 4
    for (int i = 0; i < 64; ++i) {
      unsigned tv = *(const unsigned*)(Tb + (size_t)(n0 + i) * M_NU + m0);
      float wv = sh[i];
      a0 = fmaf(bf2f((unsigned short)(tv & 0xffffu)), wv, a0);
      a1 = fmaf(bf2f((unsigned short)(tv >> 16)), wv, a1);
    }
    *(float2*)(partial + (size_t)by * M_NU + m0) = make_float2(a0, a1);
  } else {                             // ---- T/D over 128 rows
    int n = (b - 256) * 128 + (tid & 127);
    float tl = 0.f, dl = 0.f;
    if (tid < 128) {
      float rs = 0.f, wl = 0.f;
      #pragma unroll 4
      for (int cb = 0; cb < 128; ++cb) {
        rs += pr [(size_t)cb * N_PTR + n];
        wl += pr2[(size_t)cb * N_PTR + n];
      }
      float wi = 1.0f / (rs + EPS_);
      tl = rs * wi; dl = wl * wi;
    }
    __syncthreads();                   // reuse sh as red scratch
    #pragma unroll
    for (int off = 32; off > 0; off >>= 1) { tl += __shfl_down(tl, off); dl += __shfl_down(dl, off); }
    if ((tid & 63) == 0) { sh[tid >> 6] = tl; sh[4 + (tid >> 6)] = dl; }
    __syncthreads();
    if (tid == 0) {
      T_part[b - 256] = sh[0] + sh[1] + sh[2] + sh[3];
      D_part[b - 256] = sh[4] + sh[5] + sh[6] + sh[7];
    }
  }
}

// ---------- 4. final: blocks 0..15 scaled probs; block 16 scalars ----------
__global__ __launch_bounds__(256) void final_kernel(const float* __restrict__ partial,
    const float* __restrict__ T_part, const float* __restrict__ D_part,
    const float* __restrict__ s_part, const float* __restrict__ gy_part,
    float* __restrict__ out) {
  __shared__ float red[4];
  int b = blockIdx.x, tid = threadIdx.x;
  float T = 0.f;
  #pragma unroll
  for (int i = 0; i < 16; ++i) T += T_part[i];
  float scale = (1.0f / (float)N_PTR) / (T / (float)N_PTR + EPS_);
  if (b < 16) {
    int m = b * 256 + tid;
    float raw = 0.f;
    #pragma unroll
    for (int c = 0; c < 32; ++c) raw += partial[(size_t)c * M_NU + m];
    out[2 + m] = raw * scale;
  } else {
    float D = 0.f;
    #pragma unroll
    for (int i = 0; i < 16; ++i) D += D_part[i];
    float ls = 0.f, lg = 0.f;
    for (int i = tid; i < 1024; i += 256) { ls += s_part[i]; lg += gy_part[i]; }
    float S  = blk_reduce_sum(ls, red);
    float Gy = blk_reduce_sum(lg, red);
    if (tid == 0) {
      float dro = D * scale;
      const float invNM = 1.0f / ((float)N_PTR * (float)M_NU);
      float mcx = 1.f - S * invNM;
      float mcy = 1.f - Gy * invNM;
      out[0] = dro;
      out[1] = dro;
      out[2 + M_NU] = mcx + mcy;
      out[3 + M_NU] = mcx;
      out[4 + M_NU] = mcy;
    }
  }
}

extern "C" void kernel_launch(void* const* d_in, const int* in_sizes, int n_in,
                              void* d_out, int out_size, void* d_ws, size_t ws_size,
                              hipStream_t stream) {
  const float* ptr_feat = (const float*)d_in[0];
  const int*   ptr_lab  = (const int*)d_in[2];
  const float* nu_feat  = (const float*)d_in[3];
  const float* nu_log   = (const float*)d_in[4];
  const int*   nu_lab   = (const int*)d_in[5];
  const float* cls_w    = (const float*)d_in[6];
  float* out = (float*)d_out;

  char* base = (char*)d_ws;
  unsigned short* Tb  = (unsigned short*)base;                         // 16 MB
  unsigned short* Gfb = (unsigned short*)(base + 16u * 1024 * 1024);   // 2 MB (bf16 gram)
  unsigned short* An  = (unsigned short*)(base + 18u * 1024 * 1024);   // 2 MB
  unsigned short* Bn  = (unsigned short*)(base + 20u * 1024 * 1024);   // 4 MB
  unsigned short* Cn  = (unsigned short*)(base + 24u * 1024 * 1024);   // 1 MB
  float* fb           = (float*)(base + 25u * 1024 * 1024);
  float* nloss   = fb;                           // 4096
  unsigned* gbits= (unsigned*)(nloss + 4096);    // 1 (+63 pad)
  float* pr      = nloss + 4096 + 64;            // 128 * 2048
  float* pr2     = pr  + 128 * N_PTR;            // 128 * 2048
  float* partial = pr2 + 128 * N_PTR;            // 32 * 4096
  float* s_part  = partial + 32 * M_NU;          // 1024
  float* gy_part = s_part + 1024;                // 1024
  float* T_part  = gy_part + 1024;               // 16
  float* D_part  = T_part + 16;                  // 16

  prep_kernel<<<dim3(1792 + M_NU), 256, 0, stream>>>(
      ptr_feat, nu_feat, cls_w, nu_log, nu_lab, An, Bn, Cn, nloss);
  mfma_gemm<64, 64, 0><<<dim3(KPAD / 64, KPAD / 64), 256, 0, stream>>>(
      Cn, Cn, Gfb, nullptr, nullptr, nullptr, nloss, gbits,
      nullptr, nullptr, nullptr, nullptr, KPAD);
  mfma_gemm<128, 64, 1><<<dim3(1024), 256, 0, stream>>>(
      An, Bn, Gfb, Tb, ptr_lab, nu_lab, nloss, gbits,
      pr, pr2, s_part, gy_part, M_NU);
  colpass_td_kernel<<<dim3(272), 256, 0, stream>>>(Tb, pr, pr2, partial, T_part, D_part);
  final_kernel<<<dim3(17), 256, 0, stream>>>(partial, T_part, D_part, s_part, gy_part, out);
}

// Round 16
// 61.720 us; speedup vs baseline: 1.0768x; 1.0768x over previous
//
#include <hip/hip_runtime.h>
#include <math.h>

#define N_PTR 2048
#define M_NU  4096
#define DIM   512
#define KCLS  1000
#define KPAD  1024

static constexpr float LAMBDA_ = 0.1f;
static constexpr float EPS_ = 1e-8f;
static constexpr float INV_DENOM = 1.0f / (0.1f * 0.5f + 1e-8f);   // 1/(lambda*eps+EPS)

typedef short short8 __attribute__((ext_vector_type(8)));
typedef unsigned short u16x8 __attribute__((ext_vector_type(8)));
typedef float f32x4 __attribute__((ext_vector_type(4)));

__device__ __forceinline__ unsigned short f2bf(float x) {
  unsigned u = __float_as_uint(x);
  u += 0x7fff + ((u >> 16) & 1);     // round-to-nearest-even
  return (unsigned short)(u >> 16);
}
__device__ __forceinline__ float bf2f(unsigned short h) {
  return __uint_as_float(((unsigned)h) << 16);
}

__device__ __forceinline__ void gload16(const void* g, void* l) {
  __builtin_amdgcn_global_load_lds(
      (const __attribute__((address_space(1))) unsigned int*)g,
      (__attribute__((address_space(3))) unsigned int*)l, 16, 0, 0);
}

// ---------- block reduction helpers (blockDim.x == 256) ----------
__device__ __forceinline__ float blk_reduce_sum(float v, float* red) {
  #pragma unroll
  for (int off = 32; off > 0; off >>= 1) v += __shfl_down(v, off);
  __syncthreads();
  if ((threadIdx.x & 63) == 0) red[threadIdx.x >> 6] = v;
  __syncthreads();
  return red[0] + red[1] + red[2] + red[3];
}

__device__ __forceinline__ float blk_reduce_max(float v, float* red) {
  #pragma unroll
  for (int off = 32; off > 0; off >>= 1) v = fmaxf(v, __shfl_down(v, off));
  __syncthreads();
  if ((threadIdx.x & 63) == 0) red[threadIdx.x >> 6] = v;
  __syncthreads();
  return fmaxf(fmaxf(red[0], red[1]), fmaxf(red[2], red[3]));
}

// ---------- 1. fused prep: normalize+cast (blocks 0..1791) + CE loss (blocks 1792..5887) ----------
__global__ __launch_bounds__(256) void prep_kernel(
    const float* __restrict__ ptr_f, const float* __restrict__ nu_f,
    const float* __restrict__ cls_f, const float* __restrict__ logits,
    const int* __restrict__ labels, unsigned short* __restrict__ An,
    unsigned short* __restrict__ Bn, unsigned short* __restrict__ Cn,
    float* __restrict__ losses) {
  __shared__ float red[4];
  int b = blockIdx.x;
  if (b < 1792) {                       // ---- normalize + bf16 cast
    int gid = b * 256 + threadIdx.x;
    int row = gid >> 6, lane = gid & 63;
    const float* src; unsigned short* dst; int lrow; int in_rows;
    if (row < N_PTR)             { src = ptr_f; dst = An; lrow = row;                in_rows = N_PTR; }
    else if (row < N_PTR + M_NU) { src = nu_f;  dst = Bn; lrow = row - N_PTR;        in_rows = M_NU; }
    else                         { src = cls_f; dst = Cn; lrow = row - N_PTR - M_NU; in_rows = KCLS; }
    u16x8 ov;
    if (lrow < in_rows) {
      const float4* rp = (const float4*)(src + (size_t)lrow * DIM);
      float4 a = rp[lane * 2], bq = rp[lane * 2 + 1];
      float v[8] = {a.x, a.y, a.z, a.w, bq.x, bq.y, bq.z, bq.w};
      float s = 0.f;
      #pragma unroll
      for (int j = 0; j < 8; ++j) s = fmaf(v[j], v[j], s);
      #pragma unroll
      for (int off = 32; off > 0; off >>= 1) s += __shfl_xor(s, off);
      float inv = 1.0f / fmaxf(sqrtf(s), EPS_);
      #pragma unroll
      for (int j = 0; j < 8; ++j) ov[j] = f2bf(v[j] * inv);
    } else {
      #pragma unroll
      for (int j = 0; j < 8; ++j) ov[j] = 0;
    }
    *(u16x8*)(dst + (size_t)lrow * DIM + lane * 8) = ov;
  } else {                              // ---- CE loss (one block per nu row, float4 reads)
    int row = b - 1792;
    int tid = threadIdx.x;
    const float* x = logits + (size_t)row * KCLS;
    const float4* x4 = (const float4*)x;          // 4000B rows are 16B-aligned
    float4 v = make_float4(0.f, 0.f, 0.f, 0.f);
    float mx_loc = -INFINITY;
    if (tid < 250) {                              // 250*4 = 1000
      v = x4[tid];
      mx_loc = fmaxf(fmaxf(v.x, v.y), fmaxf(v.z, v.w));
    }
    float mx = blk_reduce_max(mx_loc, red);
    float se_loc = 0.f;
    if (tid < 250)
      se_loc = __expf(v.x - mx) + __expf(v.y - mx) + __expf(v.z - mx) + __expf(v.w - mx);
    float se = blk_reduce_sum(se_loc, red);
    if (tid == 0) losses[row] = mx + logf(se) - x[labels[row]];
  }
}

// ---------- 2. bf16 MFMA GEMM C = A @ B^T, tile BMxBM, BK=64, 4 waves 2x2 ----------
// DOUBLE-BUFFERED LDS, issue-early staging: per K-iter {barrier; stage(next buf);
// compute(cur buf)} — next-tile load latency overlaps ds_read+MFMA. One barrier/iter;
// __syncthreads' automatic vmcnt(0) drain guarantees buf readiness (no asm waitcnt).
// MODE 0 (G-GEMM): 2D grid; bf16 gram store; block(0,0) reduces gmax first.
// MODE 1 (S-GEMM): 1D grid, bijective XCD-chunked swizzle; fused DRO epilogue (r14).
template <int BM, int MODE>
__global__ __launch_bounds__(256) void mfma_gemm(
    const unsigned short* __restrict__ A, const unsigned short* __restrict__ B,
    unsigned short* __restrict__ Gfb, unsigned short* __restrict__ Tb,
    const int* __restrict__ pl, const int* __restrict__ nl,
    const float* __restrict__ nu_loss, unsigned* __restrict__ gbits,
    float* __restrict__ pr, float* __restrict__ pr2,
    float* __restrict__ s_part, float* __restrict__ gy_part, int ldc) {
  constexpr int FR = BM / 32;          // frags per wave dim (128->4, 64->2)
  constexpr int WSPAN = BM / 2;
  __shared__ unsigned short Alds[2][BM * 64];
  __shared__ unsigned short Blds[2][BM * 64];
  __shared__ float red[4];
  const int tid = threadIdx.x;
  const int w = tid >> 6, lane = tid & 63;
  int bx, by;
  if (MODE == 1) {
    int swz = (blockIdx.x & 7) * 64 + (blockIdx.x >> 3);   // bijective, 512 blocks
    bx = swz >> 4;                     // 0..31: XCD k owns bx in [4k, 4k+4)
    by = swz & 15;                     // 0..15
  } else {
    bx = blockIdx.x; by = blockIdx.y;
  }
  const int brow = by * BM, bcol = bx * BM;
  const int wr = w >> 1, wc = w & 1;

  if (MODE == 0 && blockIdx.x == 0 && blockIdx.y == 0) {
    float mloc = 0.f;
    for (int i = tid; i < M_NU; i += 256) mloc = fmaxf(mloc, nu_loss[i]);
    float mx = blk_reduce_max(mloc, red);
    if (tid == 0) *gbits = __float_as_uint(mx);
    __syncthreads();
  }

  const int sr = lane >> 3;            // row within 8-row staging group
  const int sc = lane & 7;             // 16B chunk within 128B row
  const int schunk = (sc ^ sr) * 8;    // pre-swizzled global element offset

  f32x4 acc[FR][FR] = {};

  // stage one 64-wide K-tile into buffer `buf`
  auto stage = [&](int buf, int k0) {
    #pragma unroll
    for (int i = 0; i < FR; ++i) {
      int j = w * FR + i;              // staging slot, 8 rows each
      int r = j * 8 + sr;
      gload16(A + (size_t)(brow + r) * DIM + k0 + schunk, (char*)Alds[buf] + j * 1024);
      gload16(B + (size_t)(bcol + r) * DIM + k0 + schunk, (char*)Blds[buf] + j * 1024);
    }
  };

  stage(0, 0);                         // prologue

  for (int kt = 0; kt < DIM / 64; ++kt) {
    const int cur = kt & 1;
    __syncthreads();                   // vmcnt(0) drain -> buf[cur] ready; buf[cur^1] free
    if (kt < DIM / 64 - 1) stage(cur ^ 1, (kt + 1) * 64);
    #pragma unroll
    for (int kk = 0; kk < 2; ++kk) {
      const int koff = kk * 64 + (lane >> 4) * 16;
      short8 af[FR], bfr[FR];
      #pragma unroll
      for (int mi = 0; mi < FR; ++mi) {
        int r = wr * WSPAN + mi * 16 + (lane & 15);
        af[mi] = *(const short8*)((const char*)Alds[cur] + r * 128 + (koff ^ ((r & 7) << 4)));
      }
      #pragma unroll
      for (int ni = 0; ni < FR; ++ni) {
        int r = wc * WSPAN + ni * 16 + (lane & 15);
        bfr[ni] = *(const short8*)((const char*)Blds[cur] + r * 128 + (koff ^ ((r & 7) << 4)));
      }
      #pragma unroll
      for (int mi = 0; mi < FR; ++mi)
        #pragma unroll
        for (int ni = 0; ni < FR; ++ni)
          acc[mi][ni] = __builtin_amdgcn_mfma_f32_16x16x32_bf16(af[mi], bfr[ni], acc[mi][ni], 0, 0, 0);
    }
  }

  // C/D layout: col = lane&15, row = (lane>>4)*4 + reg  [verified]
  if (MODE == 0) {
    #pragma unroll
    for (int mi = 0; mi < FR; ++mi)
      #pragma unroll
      for (int ni = 0; ni < FR; ++ni)
        #pragma unroll
        for (int j = 0; j < 4; ++j) {
          int row = brow + wr * WSPAN + mi * 16 + (lane >> 4) * 4 + j;
          int col = bcol + wc * WSPAN + ni * 16 + (lane & 15);
          Gfb[(size_t)row * ldc + col] = f2bf(acc[mi][ni][j]);
        }
  } else {
    const float gmax = __uint_as_float(*gbits);
    const float fac = LAMBDA_ * INV_DENOM;            // ~2
    int cols[FR]; float a_r[FR]; float loss_r[FR]; int nl_r[FR];
    #pragma unroll
    for (int ni = 0; ni < FR; ++ni) {
      cols[ni]  = bcol + wc * WSPAN + ni * 16 + (lane & 15);
      loss_r[ni] = nu_loss[cols[ni]];
      a_r[ni]   = (loss_r[ni] - gmax - 2.f * LAMBDA_) * INV_DENOM;
      nl_r[ni]  = nl[cols[ni]];
    }
    float s_acc = 0.f, gy_acc = 0.f;
    #pragma unroll
    for (int mi = 0; mi < FR; ++mi) {
      #pragma unroll
      for (int j = 0; j < 4; ++j) {
        int row = brow + wr * WSPAN + mi * 16 + (lane >> 4) * 4 + j;
        const unsigned short* Grow = Gfb + (size_t)pl[row] * KPAD;
        float rowacc = 0.f, rowacc2 = 0.f;
        #pragma unroll
        for (int ni = 0; ni < FR; ++ni) {
          float s  = acc[mi][ni][j];
          float gy = bf2f(Grow[nl_r[ni]]);
          float e  = fmaf(fac, s + gy, a_r[ni]);
          float t  = __expf(e);
          unsigned short tb = f2bf(t);
          Tb[(size_t)row * ldc + cols[ni]] = tb;
          float tt = bf2f(tb);
          rowacc  += tt;
          rowacc2 += tt * loss_r[ni];
          s_acc += s; gy_acc += gy;
        }
        #pragma unroll
        for (int off = 1; off < 16; off <<= 1) {
          rowacc  += __shfl_xor(rowacc, off);
          rowacc2 += __shfl_xor(rowacc2, off);
        }
        if ((lane & 15) == 0) {
          pr [(size_t)(bx * 2 + wc) * N_PTR + row] = rowacc;
          pr2[(size_t)(bx * 2 + wc) * N_PTR + row] = rowacc2;
        }
      }
    }
    float stot = blk_reduce_sum(s_acc, red);
    float gtot = blk_reduce_sum(gy_acc, red);
    if (tid == 0) {
      int bid = by * 32 + bx;
      s_part[bid] = stot; gy_part[bid] = gtot;
    }
  }
}

// ---------- 3. colpass (blocks 0..255) + T/D row reduce (blocks 256..271) ----------
__global__ __launch_bounds__(256) void colpass_td_kernel(
    const unsigned short* __restrict__ Tb, const float* __restrict__ pr,
    const float* __restrict__ pr2, float* __restrict__ partial,
    float* __restrict__ T_part, float* __restrict__ D_part) {
  __shared__ float sh[64];
  int b = blockIdx.x, tid = threadIdx.x;
  if (b < 256) {                       // ---- column partial: 512 m-cols x 64 n-rows
    int bx = b & 7, by = b >> 3;
    int m0 = bx * 512 + tid * 2;
    int n0 = by * 64;
    if (tid < 64) {
      float rs = 0.f;
      #pragma unroll 4
      for (int cb = 0; cb < 64; ++cb) rs += pr[(size_t)cb * N_PTR + n0 + tid];
      sh[tid] = 1.0f / (rs + EPS_);
    }
    __syncthreads();
    float a0 = 0.f, a1 = 0.f;
    #pragma unroll 4
    for (int i = 0; i < 64; ++i) {
      unsigned tv = *(const unsigned*)(Tb + (size_t)(n0 + i) * M_NU + m0);
      float wv = sh[i];
      a0 = fmaf(bf2f((unsigned short)(tv & 0xffffu)), wv, a0);
      a1 = fmaf(bf2f((unsigned short)(tv >> 16)), wv, a1);
    }
    *(float2*)(partial + (size_t)by * M_NU + m0) = make_float2(a0, a1);
  } else {                             // ---- T/D over 128 rows
    int n = (b - 256) * 128 + (tid & 127);
    float tl = 0.f, dl = 0.f;
    if (tid < 128) {
      float rs = 0.f, wl = 0.f;
      #pragma unroll 4
      for (int cb = 0; cb < 64; ++cb) {
        rs += pr [(size_t)cb * N_PTR + n];
        wl += pr2[(size_t)cb * N_PTR + n];
      }
      float wi = 1.0f / (rs + EPS_);
      tl = rs * wi; dl = wl * wi;
    }
    __syncthreads();                   // reuse sh as red scratch
    #pragma unroll
    for (int off = 32; off > 0; off >>= 1) { tl += __shfl_down(tl, off); dl += __shfl_down(dl, off); }
    if ((tid & 63) == 0) { sh[tid >> 6] = tl; sh[4 + (tid >> 6)] = dl; }
    __syncthreads();
    if (tid == 0) {
      T_part[b - 256] = sh[0] + sh[1] + sh[2] + sh[3];
      D_part[b - 256] = sh[4] + sh[5] + sh[6] + sh[7];
    }
  }
}

// ---------- 4. final: blocks 0..15 scaled probs; block 16 scalars ----------
__global__ __launch_bounds__(256) void final_kernel(const float* __restrict__ partial,
    const float* __restrict__ T_part, const float* __restrict__ D_part,
    const float* __restrict__ s_part, const float* __restrict__ gy_part,
    float* __restrict__ out) {
  __shared__ float red[4];
  int b = blockIdx.x, tid = threadIdx.x;
  float T = 0.f;
  #pragma unroll
  for (int i = 0; i < 16; ++i) T += T_part[i];
  float scale = (1.0f / (float)N_PTR) / (T / (float)N_PTR + EPS_);
  if (b < 16) {
    int m = b * 256 + tid;
    float raw = 0.f;
    #pragma unroll
    for (int c = 0; c < 32; ++c) raw += partial[(size_t)c * M_NU + m];
    out[2 + m] = raw * scale;
  } else {
    float D = 0.f;
    #pragma unroll
    for (int i = 0; i < 16; ++i) D += D_part[i];
    float ls = 0.f, lg = 0.f;
    for (int i = tid; i < 512; i += 256) { ls += s_part[i]; lg += gy_part[i]; }
    float S  = blk_reduce_sum(ls, red);
    float Gy = blk_reduce_sum(lg, red);
    if (tid == 0) {
      float dro = D * scale;
      const float invNM = 1.0f / ((float)N_PTR * (float)M_NU);
      float mcx = 1.f - S * invNM;
      float mcy = 1.f - Gy * invNM;
      out[0] = dro;
      out[1] = dro;
      out[2 + M_NU] = mcx + mcy;
      out[3 + M_NU] = mcx;
      out[4 + M_NU] = mcy;
    }
  }
}

extern "C" void kernel_launch(void* const* d_in, const int* in_sizes, int n_in,
                              void* d_out, int out_size, void* d_ws, size_t ws_size,
                              hipStream_t stream) {
  const float* ptr_feat = (const float*)d_in[0];
  const int*   ptr_lab  = (const int*)d_in[2];
  const float* nu_feat  = (const float*)d_in[3];
  const float* nu_log   = (const float*)d_in[4];
  const int*   nu_lab   = (const int*)d_in[5];
  const float* cls_w    = (const float*)d_in[6];
  float* out = (float*)d_out;

  char* base = (char*)d_ws;
  unsigned short* Tb  = (unsigned short*)base;                         // 16 MB
  unsigned short* Gfb = (unsigned short*)(base + 16u * 1024 * 1024);   // 2 MB (bf16 gram)
  unsigned short* An  = (unsigned short*)(base + 18u * 1024 * 1024);   // 2 MB
  unsigned short* Bn  = (unsigned short*)(base + 20u * 1024 * 1024);   // 4 MB
  unsigned short* Cn  = (unsigned short*)(base + 24u * 1024 * 1024);   // 1 MB
  float* fb           = (float*)(base + 25u * 1024 * 1024);
  float* nloss   = fb;                           // 4096
  unsigned* gbits= (unsigned*)(nloss + 4096);    // 1 (+63 pad)
  float* pr      = nloss + 4096 + 64;            // 64 * 2048
  float* pr2     = pr  + 64 * N_PTR;             // 64 * 2048
  float* partial = pr2 + 64 * N_PTR;             // 32 * 4096
  float* s_part  = partial + 32 * M_NU;          // 512
  float* gy_part = s_part + 512;                 // 512
  float* T_part  = gy_part + 512;                // 16
  float* D_part  = T_part + 16;                  // 16

  prep_kernel<<<dim3(1792 + M_NU), 256, 0, stream>>>(
      ptr_feat, nu_feat, cls_w, nu_log, nu_lab, An, Bn, Cn, nloss);
  mfma_gemm<64, 0><<<dim3(KPAD / 64, KPAD / 64), 256, 0, stream>>>(
      Cn, Cn, Gfb, nullptr, nullptr, nullptr, nloss, gbits,
      nullptr, nullptr, nullptr, nullptr, KPAD);
  mfma_gemm<128, 1><<<dim3(512), 256, 0, stream>>>(
      An, Bn, Gfb, Tb, ptr_lab, nu_lab, nloss, gbits,
      pr, pr2, s_part, gy_part, M_NU);
  colpass_td_kernel<<<dim3(272), 256, 0, stream>>>(Tb, pr, pr2, partial, T_part, D_part);
  final_kernel<<<dim3(17), 256, 0, stream>>>(partial, T_part, D_part, s_part, gy_part, out);
}

// Round 17
// 61.419 us; speedup vs baseline: 1.0820x; 1.0049x over previous
//
#include <hip/hip_runtime.h>
#include <math.h>

#define N_PTR 2048
#define M_NU  4096
#define DIM   512
#define KCLS  1000
#define KPAD  1024

static constexpr float LAMBDA_ = 0.1f;
static constexpr float EPS_ = 1e-8f;
static constexpr float INV_DENOM = 1.0f / (0.1f * 0.5f + 1e-8f);   // 1/(lambda*eps+EPS)

typedef short short8 __attribute__((ext_vector_type(8)));
typedef unsigned short u16x8 __attribute__((ext_vector_type(8)));
typedef float f32x4 __attribute__((ext_vector_type(4)));

__device__ __forceinline__ unsigned short f2bf(float x) {
  unsigned u = __float_as_uint(x);
  u += 0x7fff + ((u >> 16) & 1);     // round-to-nearest-even
  return (unsigned short)(u >> 16);
}
__device__ __forceinline__ float bf2f(unsigned short h) {
  return __uint_as_float(((unsigned)h) << 16);
}

__device__ __forceinline__ void gload16(const void* g, void* l) {
  __builtin_amdgcn_global_load_lds(
      (const __attribute__((address_space(1))) unsigned int*)g,
      (__attribute__((address_space(3))) unsigned int*)l, 16, 0, 0);
}

// ---------- block reduction helpers (blockDim.x == 256) ----------
__device__ __forceinline__ float blk_reduce_sum(float v, float* red) {
  #pragma unroll
  for (int off = 32; off > 0; off >>= 1) v += __shfl_down(v, off);
  __syncthreads();
  if ((threadIdx.x & 63) == 0) red[threadIdx.x >> 6] = v;
  __syncthreads();
  return red[0] + red[1] + red[2] + red[3];
}

__device__ __forceinline__ float blk_reduce_max(float v, float* red) {
  #pragma unroll
  for (int off = 32; off > 0; off >>= 1) v = fmaxf(v, __shfl_down(v, off));
  __syncthreads();
  if ((threadIdx.x & 63) == 0) red[threadIdx.x >> 6] = v;
  __syncthreads();
  return fmaxf(fmaxf(red[0], red[1]), fmaxf(red[2], red[3]));
}

// ---------- 1. fused prep: normalize+cast (blocks 0..1791) + CE loss (blocks 1792..2815) ----------
// CE: one WAVE per nu row (shfl-only reductions, no barriers). [validated r6/r7]
__global__ __launch_bounds__(256) void prep_kernel(
    const float* __restrict__ ptr_f, const float* __restrict__ nu_f,
    const float* __restrict__ cls_f, const float* __restrict__ logits,
    const int* __restrict__ labels, unsigned short* __restrict__ An,
    unsigned short* __restrict__ Bn, unsigned short* __restrict__ Cn,
    float* __restrict__ losses) {
  int b = blockIdx.x;
  int tid = threadIdx.x;
  if (b < 1792) {                       // ---- normalize + bf16 cast, one wave per row
    int gid = b * 256 + tid;
    int row = gid >> 6, lane = gid & 63;
    const float* src; unsigned short* dst; int lrow; int in_rows;
    if (row < N_PTR)             { src = ptr_f; dst = An; lrow = row;                in_rows = N_PTR; }
    else if (row < N_PTR + M_NU) { src = nu_f;  dst = Bn; lrow = row - N_PTR;        in_rows = M_NU; }
    else                         { src = cls_f; dst = Cn; lrow = row - N_PTR - M_NU; in_rows = KCLS; }
    u16x8 ov;
    if (lrow < in_rows) {
      const float4* rp = (const float4*)(src + (size_t)lrow * DIM);
      float4 a = rp[lane * 2], bq = rp[lane * 2 + 1];
      float v[8] = {a.x, a.y, a.z, a.w, bq.x, bq.y, bq.z, bq.w};
      float s = 0.f;
      #pragma unroll
      for (int j = 0; j < 8; ++j) s = fmaf(v[j], v[j], s);
      #pragma unroll
      for (int off = 32; off > 0; off >>= 1) s += __shfl_xor(s, off);
      float inv = 1.0f / fmaxf(sqrtf(s), EPS_);
      #pragma unroll
      for (int j = 0; j < 8; ++j) ov[j] = f2bf(v[j] * inv);
    } else {
      #pragma unroll
      for (int j = 0; j < 8; ++j) ov[j] = 0;
    }
    *(u16x8*)(dst + (size_t)lrow * DIM + lane * 8) = ov;
  } else {                              // ---- CE loss, one wave per row
    int row = (b - 1792) * 4 + (tid >> 6);
    int lane = tid & 63;
    const float4* x4 = (const float4*)(logits + (size_t)row * KCLS);  // 250 float4
    float4 v0 = x4[lane], v1 = x4[lane + 64], v2 = x4[lane + 128];
    bool has3 = lane < 58;
    float4 v3 = has3 ? x4[lane + 192] : make_float4(0.f, 0.f, 0.f, 0.f);
    float mx = fmaxf(fmaxf(fmaxf(v0.x, v0.y), fmaxf(v0.z, v0.w)),
               fmaxf(fmaxf(fmaxf(v1.x, v1.y), fmaxf(v1.z, v1.w)),
                     fmaxf(fmaxf(v2.x, v2.y), fmaxf(v2.z, v2.w))));
    if (has3) mx = fmaxf(mx, fmaxf(fmaxf(v3.x, v3.y), fmaxf(v3.z, v3.w)));
    #pragma unroll
    for (int off = 32; off > 0; off >>= 1) mx = fmaxf(mx, __shfl_xor(mx, off));
    float se = __expf(v0.x - mx) + __expf(v0.y - mx) + __expf(v0.z - mx) + __expf(v0.w - mx)
             + __expf(v1.x - mx) + __expf(v1.y - mx) + __expf(v1.z - mx) + __expf(v1.w - mx)
             + __expf(v2.x - mx) + __expf(v2.y - mx) + __expf(v2.z - mx) + __expf(v2.w - mx);
    if (has3)
      se += __expf(v3.x - mx) + __expf(v3.y - mx) + __expf(v3.z - mx) + __expf(v3.w - mx);
    #pragma unroll
    for (int off = 32; off > 0; off >>= 1) se += __shfl_xor(se, off);
    if (lane == 0)
      losses[row] = mx + logf(se) - logits[(size_t)row * KCLS + labels[row]];
  }
}

// ---------- 2. bf16 MFMA GEMM C = A @ B^T, tile BMxBM, BK=64, 4 waves 2x2 ----------
// DOUBLE-BUFFERED LDS, issue-early staging (r16-validated).
// MODE 0 (G-GEMM): 2D grid; bf16 gram store; block(0,0) reduces gmax first.
// MODE 1 (S-GEMM): 1D grid, bijective XCD-chunked swizzle; fused DRO epilogue (r14).
template <int BM, int MODE>
__global__ __launch_bounds__(256) void mfma_gemm(
    const unsigned short* __restrict__ A, const unsigned short* __restrict__ B,
    unsigned short* __restrict__ Gfb, unsigned short* __restrict__ Tb,
    const int* __restrict__ pl, const int* __restrict__ nl,
    const float* __restrict__ nu_loss, unsigned* __restrict__ gbits,
    float* __restrict__ pr, float* __restrict__ pr2,
    float* __restrict__ s_part, float* __restrict__ gy_part, int ldc) {
  constexpr int FR = BM / 32;          // frags per wave dim (128->4, 64->2)
  constexpr int WSPAN = BM / 2;
  __shared__ unsigned short Alds[2][BM * 64];
  __shared__ unsigned short Blds[2][BM * 64];
  __shared__ float red[4];
  const int tid = threadIdx.x;
  const int w = tid >> 6, lane = tid & 63;
  int bx, by;
  if (MODE == 1) {
    int swz = (blockIdx.x & 7) * 64 + (blockIdx.x >> 3);   // bijective, 512 blocks
    bx = swz >> 4;                     // 0..31: XCD k owns bx in [4k, 4k+4)
    by = swz & 15;                     // 0..15
  } else {
    bx = blockIdx.x; by = blockIdx.y;
  }
  const int brow = by * BM, bcol = bx * BM;
  const int wr = w >> 1, wc = w & 1;

  if (MODE == 0 && blockIdx.x == 0 && blockIdx.y == 0) {
    float mloc = 0.f;
    for (int i = tid; i < M_NU; i += 256) mloc = fmaxf(mloc, nu_loss[i]);
    float mx = blk_reduce_max(mloc, red);
    if (tid == 0) *gbits = __float_as_uint(mx);
    __syncthreads();
  }

  const int sr = lane >> 3;            // row within 8-row staging group
  const int sc = lane & 7;             // 16B chunk within 128B row
  const int schunk = (sc ^ sr) * 8;    // pre-swizzled global element offset

  f32x4 acc[FR][FR] = {};

  // stage one 64-wide K-tile into buffer `buf`
  auto stage = [&](int buf, int k0) {
    #pragma unroll
    for (int i = 0; i < FR; ++i) {
      int j = w * FR + i;              // staging slot, 8 rows each
      int r = j * 8 + sr;
      gload16(A + (size_t)(brow + r) * DIM + k0 + schunk, (char*)Alds[buf] + j * 1024);
      gload16(B + (size_t)(bcol + r) * DIM + k0 + schunk, (char*)Blds[buf] + j * 1024);
    }
  };

  stage(0, 0);                         // prologue

  for (int kt = 0; kt < DIM / 64; ++kt) {
    const int cur = kt & 1;
    __syncthreads();                   // vmcnt(0) drain -> buf[cur] ready; buf[cur^1] free
    if (kt < DIM / 64 - 1) stage(cur ^ 1, (kt + 1) * 64);
    #pragma unroll
    for (int kk = 0; kk < 2; ++kk) {
      const int koff = kk * 64 + (lane >> 4) * 16;
      short8 af[FR], bfr[FR];
      #pragma unroll
      for (int mi = 0; mi < FR; ++mi) {
        int r = wr * WSPAN + mi * 16 + (lane & 15);
        af[mi] = *(const short8*)((const char*)Alds[cur] + r * 128 + (koff ^ ((r & 7) << 4)));
      }
      #pragma unroll
      for (int ni = 0; ni < FR; ++ni) {
        int r = wc * WSPAN + ni * 16 + (lane & 15);
        bfr[ni] = *(const short8*)((const char*)Blds[cur] + r * 128 + (koff ^ ((r & 7) << 4)));
      }
      #pragma unroll
      for (int mi = 0; mi < FR; ++mi)
        #pragma unroll
        for (int ni = 0; ni < FR; ++ni)
          acc[mi][ni] = __builtin_amdgcn_mfma_f32_16x16x32_bf16(af[mi], bfr[ni], acc[mi][ni], 0, 0, 0);
    }
  }

  // C/D layout: col = lane&15, row = (lane>>4)*4 + reg  [verified]
  if (MODE == 0) {
    #pragma unroll
    for (int mi = 0; mi < FR; ++mi)
      #pragma unroll
      for (int ni = 0; ni < FR; ++ni)
        #pragma unroll
        for (int j = 0; j < 4; ++j) {
          int row = brow + wr * WSPAN + mi * 16 + (lane >> 4) * 4 + j;
          int col = bcol + wc * WSPAN + ni * 16 + (lane & 15);
          Gfb[(size_t)row * ldc + col] = f2bf(acc[mi][ni][j]);
        }
  } else {
    const float gmax = __uint_as_float(*gbits);
    const float fac = LAMBDA_ * INV_DENOM;            // ~2
    int cols[FR]; float a_r[FR]; float loss_r[FR]; int nl_r[FR];
    #pragma unroll
    for (int ni = 0; ni < FR; ++ni) {
      cols[ni]  = bcol + wc * WSPAN + ni * 16 + (lane & 15);
      loss_r[ni] = nu_loss[cols[ni]];
      a_r[ni]   = (loss_r[ni] - gmax - 2.f * LAMBDA_) * INV_DENOM;
      nl_r[ni]  = nl[cols[ni]];
    }
    float s_acc = 0.f, gy_acc = 0.f;
    #pragma unroll
    for (int mi = 0; mi < FR; ++mi) {
      #pragma unroll
      for (int j = 0; j < 4; ++j) {
        int row = brow + wr * WSPAN + mi * 16 + (lane >> 4) * 4 + j;
        const unsigned short* Grow = Gfb + (size_t)pl[row] * KPAD;
        float rowacc = 0.f, rowacc2 = 0.f;
        #pragma unroll
        for (int ni = 0; ni < FR; ++ni) {
          float s  = acc[mi][ni][j];
          float gy = bf2f(Grow[nl_r[ni]]);
          float e  = fmaf(fac, s + gy, a_r[ni]);
          float t  = __expf(e);
          unsigned short tb = f2bf(t);
          Tb[(size_t)row * ldc + cols[ni]] = tb;
          float tt = bf2f(tb);
          rowacc  += tt;
          rowacc2 += tt * loss_r[ni];
          s_acc += s; gy_acc += gy;
        }
        #pragma unroll
        for (int off = 1; off < 16; off <<= 1) {
          rowacc  += __shfl_xor(rowacc, off);
          rowacc2 += __shfl_xor(rowacc2, off);
        }
        if ((lane & 15) == 0) {
          pr [(size_t)(bx * 2 + wc) * N_PTR + row] = rowacc;
          pr2[(size_t)(bx * 2 + wc) * N_PTR + row] = rowacc2;
        }
      }
    }
    float stot = blk_reduce_sum(s_acc, red);
    float gtot = blk_reduce_sum(gy_acc, red);
    if (tid == 0) {
      int bid = by * 32 + bx;
      s_part[bid] = stot; gy_part[bid] = gtot;
    }
  }
}

// ---------- 3. colpass (blocks 0..255) + T/D row reduce (blocks 256..271) ----------
__global__ __launch_bounds__(256) void colpass_td_kernel(
    const unsigned short* __restrict__ Tb, const float* __restrict__ pr,
    const float* __restrict__ pr2, float* __restrict__ partial,
    float* __restrict__ T_part, float* __restrict__ D_part) {
  __shared__ float sh[64];
  int b = blockIdx.x, tid = threadIdx.x;
  if (b < 256) {                       // ---- column partial: 512 m-cols x 64 n-rows
    int bx = b & 7, by = b >> 3;
    int m0 = bx * 512 + tid * 2;
    int n0 = by * 64;
    if (tid < 64) {
      float rs = 0.f;
      #pragma unroll 4
      for (int cb = 0; cb < 64; ++cb) rs += pr[(size_t)cb * N_PTR + n0 + tid];
      sh[tid] = 1.0f / (rs + EPS_);
    }
    __syncthreads();
    float a0 = 0.f, a1 = 0.f;
    #pragma unroll 4
    for (int i = 0; i < 64; ++i) {
      unsigned tv = *(const unsigned*)(Tb + (size_t)(n0 + i) * M_NU + m0);
      float wv = sh[i];
      a0 = fmaf(bf2f((unsigned short)(tv & 0xffffu)), wv, a0);
      a1 = fmaf(bf2f((unsigned short)(tv >> 16)), wv, a1);
    }
    *(float2*)(partial + (size_t)by * M_NU + m0) = make_float2(a0, a1);
  } else {                             // ---- T/D over 128 rows
    int n = (b - 256) * 128 + (tid & 127);
    float tl = 0.f, dl = 0.f;
    if (tid < 128) {
      float rs = 0.f, wl = 0.f;
      #pragma unroll 4
      for (int cb = 0; cb < 64; ++cb) {
        rs += pr [(size_t)cb * N_PTR + n];
        wl += pr2[(size_t)cb * N_PTR + n];
      }
      float wi = 1.0f / (rs + EPS_);
      tl = rs * wi; dl = wl * wi;
    }
    __syncthreads();                   // reuse sh as red scratch
    #pragma unroll
    for (int off = 32; off > 0; off >>= 1) { tl += __shfl_down(tl, off); dl += __shfl_down(dl, off); }
    if ((tid & 63) == 0) { sh[tid >> 6] = tl; sh[4 + (tid >> 6)] = dl; }
    __syncthreads();
    if (tid == 0) {
      T_part[b - 256] = sh[0] + sh[1] + sh[2] + sh[3];
      D_part[b - 256] = sh[4] + sh[5] + sh[6] + sh[7];
    }
  }
}

// ---------- 4. final: blocks 0..15 scaled probs; block 16 scalars ----------
__global__ __launch_bounds__(256) void final_kernel(const float* __restrict__ partial,
    const float* __restrict__ T_part, const float* __restrict__ D_part,
    const float* __restrict__ s_part, const float* __restrict__ gy_part,
    float* __restrict__ out) {
  __shared__ float red[4];
  int b = blockIdx.x, tid = threadIdx.x;
  float T = 0.f;
  #pragma unroll
  for (int i = 0; i < 16; ++i) T += T_part[i];
  float scale = (1.0f / (float)N_PTR) / (T / (float)N_PTR + EPS_);
  if (b < 16) {
    int m = b * 256 + tid;
    float raw = 0.f;
    #pragma unroll
    for (int c = 0; c < 32; ++c) raw += partial[(size_t)c * M_NU + m];
    out[2 + m] = raw * scale;
  } else {
    float D = 0.f;
    #pragma unroll
    for (int i = 0; i < 16; ++i) D += D_part[i];
    float ls = 0.f, lg = 0.f;
    for (int i = tid; i < 512; i += 256) { ls += s_part[i]; lg += gy_part[i]; }
    float S  = blk_reduce_sum(ls, red);
    float Gy = blk_reduce_sum(lg, red);
    if (tid == 0) {
      float dro = D * scale;
      const float invNM = 1.0f / ((float)N_PTR * (float)M_NU);
      float mcx = 1.f - S * invNM;
      float mcy = 1.f - Gy * invNM;
      out[0] = dro;
      out[1] = dro;
      out[2 + M_NU] = mcx + mcy;
      out[3 + M_NU] = mcx;
      out[4 + M_NU] = mcy;
    }
  }
}

extern "C" void kernel_launch(void* const* d_in, const int* in_sizes, int n_in,
                              void* d_out, int out_size, void* d_ws, size_t ws_size,
                              hipStream_t stream) {
  const float* ptr_feat = (const float*)d_in[0];
  const int*   ptr_lab  = (const int*)d_in[2];
  const float* nu_feat  = (const float*)d_in[3];
  const float* nu_log   = (const float*)d_in[4];
  const int*   nu_lab   = (const int*)d_in[5];
  const float* cls_w    = (const float*)d_in[6];
  float* out = (float*)d_out;

  char* base = (char*)d_ws;
  unsigned short* Tb  = (unsigned short*)base;                         // 16 MB
  unsigned short* Gfb = (unsigned short*)(base + 16u * 1024 * 1024);   // 2 MB (bf16 gram)
  unsigned short* An  = (unsigned short*)(base + 18u * 1024 * 1024);   // 2 MB
  unsigned short* Bn  = (unsigned short*)(base + 20u * 1024 * 1024);   // 4 MB
  unsigned short* Cn  = (unsigned short*)(base + 24u * 1024 * 1024);   // 1 MB
  float* fb           = (float*)(base + 25u * 1024 * 1024);
  float* nloss   = fb;                           // 4096
  unsigned* gbits= (unsigned*)(nloss + 4096);    // 1 (+63 pad)
  float* pr      = nloss + 4096 + 64;            // 64 * 2048
  float* pr2     = pr  + 64 * N_PTR;             // 64 * 2048
  float* partial = pr2 + 64 * N_PTR;             // 32 * 4096
  float* s_part  = partial + 32 * M_NU;          // 512
  float* gy_part = s_part + 512;                 // 512
  float* T_part  = gy_part + 512;                // 16
  float* D_part  = T_part + 16;                  // 16

  prep_kernel<<<dim3(1792 + M_NU / 4), 256, 0, stream>>>(
      ptr_feat, nu_feat, cls_w, nu_log, nu_lab, An, Bn, Cn, nloss);
  mfma_gemm<64, 0><<<dim3(KPAD / 64, KPAD / 64), 256, 0, stream>>>(
      Cn, Cn, Gfb, nullptr, nullptr, nullptr, nloss, gbits,
      nullptr, nullptr, nullptr, nullptr, KPAD);
  mfma_gemm<128, 1><<<dim3(512), 256, 0, stream>>>(
      An, Bn, Gfb, Tb, ptr_lab, nu_lab, nloss, gbits,
      pr, pr2, s_part, gy_part, M_NU);
  colpass_td_kernel<<<dim3(272), 256, 0, stream>>>(Tb, pr, pr2, partial, T_part, D_part);
  final_kernel<<<dim3(17), 256, 0, stream>>>(partial, T_part, D_part, s_part, gy_part, out);
}